// Round 12
// baseline (661.439 us; speedup 1.0000x reference)
//
#include <hip/hip_runtime.h>

#define N 8192
#define D 512
#define KNEI 10
#define NC 8
#define GSPLIT 16
#define TRS 20
#define NTOT (GSPLIT * 2 * NC)  // 256 candidates per row

typedef __attribute__((ext_vector_type(8))) short bfv8;
typedef __attribute__((ext_vector_type(8))) unsigned short usv8;
typedef __attribute__((ext_vector_type(4))) float fv4;
typedef unsigned int uint32;

#define GLOAD_LDS16(gp, lp)                                                  \
  __builtin_amdgcn_global_load_lds(                                          \
      (const __attribute__((address_space(1))) void*)(gp),                   \
      (__attribute__((address_space(3))) void*)(lp), 16, 0, 0)

__device__ inline unsigned short f2bf(float f) {
  unsigned int u = __float_as_uint(f);
  return (unsigned short)((u + 0x7fffu + ((u >> 16) & 1u)) >> 16);
}

// ---------------------------------------------------------------------------
// Kernel 0: per-row fp32 sq (numpy-pairwise-style; validated rounds 3-11).
// ---------------------------------------------------------------------------
__global__ __launch_bounds__(256) void row_sq_np_kernel(const float* __restrict__ x,
                                                        float* __restrict__ sq) {
  const int wave = threadIdx.x >> 6;
  const int lane = threadIdx.x & 63;
  const int row = blockIdx.x * 4 + wave;
  const float* xr = x + (size_t)row * D;

  float s = 0.f;
  if (lane < 32) {
    const int leaf = lane >> 3;
    const int j = lane & 7;
    const float* a = xr + leaf * 128;
    float v = a[j];
    s = __fmul_rn(v, v);
#pragma unroll
    for (int i = 8; i < 128; i += 8) {
      v = a[i + j];
      s = __fadd_rn(s, __fmul_rn(v, v));
    }
  }
  float t1 = __shfl_xor(s, 1);
  s = __fadd_rn(s, t1);
  float t2 = __shfl_xor(s, 2);
  s = __fadd_rn(s, t2);
  float t4 = __shfl_xor(s, 4);
  s = __fadd_rn(s, t4);
  const float L0 = __shfl(s, 0);
  const float L1 = __shfl(s, 8);
  const float L2 = __shfl(s, 16);
  const float L3 = __shfl(s, 24);
  const float total = __fadd_rn(__fadd_rn(L0, L1), __fadd_rn(L2, L3));
  if (lane == 0) sq[row] = total;
}

// ---------------------------------------------------------------------------
// Kernel 0b: fp32 -> bf16 (RTNE).
// ---------------------------------------------------------------------------
__global__ __launch_bounds__(256) void cvt_bf16_kernel(const float* __restrict__ x,
                                                       unsigned short* __restrict__ xb) {
  const int base = (blockIdx.x * 256 + threadIdx.x) * 8;
  const float4 a = *(const float4*)(x + base);
  const float4 b = *(const float4*)(x + base + 4);
  usv8 o;
  o[0] = f2bf(a.x); o[1] = f2bf(a.y); o[2] = f2bf(a.z); o[3] = f2bf(a.w);
  o[4] = f2bf(b.x); o[5] = f2bf(b.y); o[6] = f2bf(b.z); o[7] = f2bf(b.w);
  *(usv8*)(xb + base) = o;
}

// ---------------------------------------------------------------------------
// Kernel 1: MFMA bf16 Gram + fused selection. Round-8 core (validated 142 µs)
// with two deltas:
//   (1) phase-split score buffer Ct[32][136] (17.4 KB, aliased inside the
//       24 KB staging) -> LDS 24.8 KB -> 6 blocks/CU (was 4).
//   (2) truncation-packed keys: bits(max(d,0)) & 0xffff0000 | j — monotone,
//       keeps the validated single-uint insert chain, no f2bf in the scan.
// ---------------------------------------------------------------------------
__global__ __launch_bounds__(256, 6) void knn_gemm_mfma(
    const unsigned short* __restrict__ xb, const float* __restrict__ sq,
    uint32* __restrict__ ck) {
  __shared__ __align__(16) char smem[24832];
  unsigned short* As = (unsigned short*)smem;            // 128x64 bf16 = 16384
  unsigned short* Bs = (unsigned short*)(smem + 16384);  // 64x64 bf16 =  8192
  float* Ct = (float*)smem;                              // [32][136] = 17408
  float* sqj_s = (float*)(smem + 24576);                 // 64 floats

  const int tid = threadIdx.x;
  const int lane = tid & 63;
  const int wave = tid >> 6;
  const int m = lane & 15;
  const int kg = lane >> 4;
  const int ibase = blockIdx.x * 128;
  const int jstart = blockIdx.y * (N / GSPLIT);

  const int srow = lane >> 3;
  const int schunk = lane & 7;
  const int sko = (schunk ^ srow) * 8;  // XOR-swizzled source k-offset

  uint32 bk[NC];
#pragma unroll
  for (int t = 0; t < NC; ++t) bk[t] = 0xffffffffu;

  const int selrow = tid & 127;
  const int selhalf = tid >> 7;
  const float sqi_own = sq[ibase + selrow];

  for (int jt = 0; jt < 8; ++jt) {
    const int jbase = jstart + jt * 64;

    fv4 acc[2][4];
#pragma unroll
    for (int fi = 0; fi < 2; ++fi)
#pragma unroll
      for (int fj = 0; fj < 4; ++fj) acc[fi][fj] = (fv4)(0.f);

    for (int kt = 0; kt < 8; ++kt) {
      const int k0 = kt * 64;
      __syncthreads();  // prior frag/Ct/sqj reads done; LDS reusable
      if (kt == 0 && tid < 64) sqj_s[tid] = sq[jbase + tid];
#pragma unroll
      for (int q = 0; q < 4; ++q) {
        const int rbase = wave * 8 + q * 32;
        GLOAD_LDS16(xb + (size_t)(ibase + rbase + srow) * D + k0 + sko,
                    As + rbase * 64);
      }
#pragma unroll
      for (int q = 0; q < 2; ++q) {
        const int rbase = wave * 8 + q * 32;
        GLOAD_LDS16(xb + (size_t)(jbase + rbase + srow) * D + k0 + sko,
                    Bs + rbase * 64);
      }
      __syncthreads();  // staging visible

      bfv8 af[2][2];
#pragma unroll
      for (int fi = 0; fi < 2; ++fi) {
        const int row = wave * 32 + fi * 16 + m;
#pragma unroll
        for (int kh = 0; kh < 2; ++kh) {
          const int ch = (kh * 4 + kg) ^ (row & 7);
          af[fi][kh] = *(const bfv8*)(As + row * 64 + ch * 8);
        }
      }
#pragma unroll
      for (int fj = 0; fj < 4; ++fj) {
        const int row = fj * 16 + m;
        const bfv8 b0 = *(const bfv8*)(Bs + row * 64 + ((kg ^ (row & 7)) * 8));
        const bfv8 b1 =
            *(const bfv8*)(Bs + row * 64 + (((4 + kg) ^ (row & 7)) * 8));
#pragma unroll
        for (int fi = 0; fi < 2; ++fi) {
          acc[fi][fj] = __builtin_amdgcn_mfma_f32_16x16x32_bf16(
              af[fi][0], b0, acc[fi][fj], 0, 0, 0);
          acc[fi][fj] = __builtin_amdgcn_mfma_f32_16x16x32_bf16(
              af[fi][1], b1, acc[fi][fj], 0, 0, 0);
        }
      }
    }

    // Two dump+scan phases (32 cols each) using Ct[32][136].
#pragma unroll 1
    for (int ph = 0; ph < 2; ++ph) {
      __syncthreads();  // ph0: frag reads done (alias OK); ph1: scan-ph0 done
      // Dump cols ph*32..+31 (C/D layout: col=lane&15, row=(lane>>4)*4+reg).
#pragma unroll
      for (int fi = 0; fi < 2; ++fi)
#pragma unroll
        for (int f = 0; f < 2; ++f) {
          const int colp = f * 16 + m;  // col within phase
          *(fv4*)(&Ct[colp * 136 + wave * 32 + fi * 16 + kg * 4]) =
              acc[fi][ph * 2 + f];
        }
      __syncthreads();

      // Scan: thread = (row, half); 16 cols of this phase per thread.
      const int cb = selhalf * 16;
#pragma unroll 1
      for (int cc = 0; cc < 16; ++cc) {
        const int cl = cb + cc;
        const float d = fmaxf(
            sqi_own - 2.f * Ct[cl * 136 + selrow] + sqj_s[ph * 32 + cl], 0.f);
        const uint32 key = (__float_as_uint(d) & 0xffff0000u) |
                           (uint32)(jbase + ph * 32 + cl);
        if (key < bk[NC - 1]) {
          uint32 kv = key;
#pragma unroll
          for (int t = 0; t < NC; ++t) {
            if (kv < bk[t]) {
              const uint32 tmp = bk[t];
              bk[t] = kv;
              kv = tmp;
            }
          }
        }
      }
    }
  }

  const size_t obase =
      ((size_t)(ibase + selrow) * (GSPLIT * 2) + blockIdx.y * 2 + selhalf) * NC;
#pragma unroll
  for (int t = 0; t < NC; ++t) ck[obase + t] = bk[t];
}

// ---------------------------------------------------------------------------
// Kernel 2: wave-per-row merge (validated rounds 8/10/11; unchanged).
// ---------------------------------------------------------------------------
__global__ __launch_bounds__(256) void merge_kernel(const float* __restrict__ x,
                                                    const float* __restrict__ sq,
                                                    const uint32* __restrict__ ck,
                                                    float* __restrict__ out) {
  __shared__ double zsh[4][TRS];
  __shared__ int jsh[4][TRS];
  __shared__ int jout[4][KNEI];

  const int wave = threadIdx.x >> 6;
  const int lane = threadIdx.x & 63;
  const int i = blockIdx.x * 4 + wave;

  const float4 xiA = *(const float4*)(x + (size_t)i * D + lane * 8);
  const float4 xiB = *(const float4*)(x + (size_t)i * D + lane * 8 + 4);
  const float sqi = sq[i];

  const uint32* ckr = ck + (size_t)i * NTOT + lane * 4;
  uint32 l0 = ckr[0], l1 = ckr[1], l2 = ckr[2], l3 = ckr[3];

  // (1) top-20 by packed key (score bits, then lower index — keys unique).
  int myselj = 0;
#pragma unroll 1
  for (int slot = 0; slot < TRS; ++slot) {
    uint32 r = min(min(l0, l1), min(l2, l3));
#pragma unroll
    for (int off = 32; off; off >>= 1) r = min(r, __shfl_xor(r, off));
    if (lane == slot) myselj = (int)(r & 0xffffu);
    if (l0 == r) l0 = 0xffffffffu;
    if (l1 == r) l1 = 0xffffffffu;
    if (l2 == r) l2 = 0xffffffffu;
    if (l3 == r) l3 = 0xffffffffu;
  }

  // (2) fp64 rescore with the reference's fp32 rounding chain (validated).
  double myz = 0.0;
#pragma unroll 4
  for (int c = 0; c < TRS; ++c) {
    const int j = __shfl(myselj, c);
    const float4 a = *(const float4*)(x + (size_t)j * D + lane * 8);
    const float4 b = *(const float4*)(x + (size_t)j * D + lane * 8 + 4);
    double s = (double)xiA.x * a.x + (double)xiA.y * a.y +
               (double)xiA.z * a.z + (double)xiA.w * a.w +
               (double)xiB.x * b.x + (double)xiB.y * b.y +
               (double)xiB.z * b.z + (double)xiB.w * b.w;
#pragma unroll
    for (int off = 32; off; off >>= 1) s += __shfl_xor(s, off);
    if (lane == c) {
      const float G = (float)s;
      const float y = __fsub_rn(sqi, __fmul_rn(2.0f, G));
      myz = (double)y + (double)sq[j];
    }
  }
  if (lane < TRS) {
    zsh[wave][lane] = myz;
    jsh[wave][lane] = myselj;
  }
  __syncthreads();

  // (3) serial top-10, eps tie-break — comparator identical to rounds 3-11.
  if (lane == 0) {
    unsigned int used = 0u;
    for (int slot = 0; slot < KNEI; ++slot) {
      int b = -1;
      double zb = 0.0;
      for (int c = 0; c < TRS; ++c) {
        if ((used >> c) & 1u) continue;
        const double zc = zsh[wave][c];
        if (b < 0) {
          b = c;
          zb = zc;
          continue;
        }
        const double eps = 1.25e-7 * fabs(zb);
        bool better;
        if (zc < zb - eps) better = true;
        else if (zc > zb + eps) better = false;
        else better = (jsh[wave][c] < jsh[wave][b]);
        if (better) {
          b = c;
          zb = zc;
        }
      }
      used |= (1u << b);
      jout[wave][slot] = jsh[wave][b];
    }
  }
  __syncthreads();

  // (4) smoothed = 0.5*x + 0.05 * sum(neighbors); 8 dims per lane.
  float4 sA = {0.f, 0.f, 0.f, 0.f}, sB = {0.f, 0.f, 0.f, 0.f};
#pragma unroll
  for (int mth = 0; mth < KNEI; ++mth) {
    const int j = jout[wave][mth];
    const float4 a = *(const float4*)(x + (size_t)j * D + lane * 8);
    const float4 b = *(const float4*)(x + (size_t)j * D + lane * 8 + 4);
    sA.x += a.x; sA.y += a.y; sA.z += a.z; sA.w += a.w;
    sB.x += b.x; sB.y += b.y; sB.z += b.z; sB.w += b.w;
  }
  float4 oA, oB;
  oA.x = 0.5f * xiA.x + 0.05f * sA.x;
  oA.y = 0.5f * xiA.y + 0.05f * sA.y;
  oA.z = 0.5f * xiA.z + 0.05f * sA.z;
  oA.w = 0.5f * xiA.w + 0.05f * sA.w;
  oB.x = 0.5f * xiB.x + 0.05f * sB.x;
  oB.y = 0.5f * xiB.y + 0.05f * sB.y;
  oB.z = 0.5f * xiB.z + 0.05f * sB.z;
  oB.w = 0.5f * xiB.w + 0.05f * sB.w;
  *(float4*)(out + (size_t)i * D + lane * 8) = oA;
  *(float4*)(out + (size_t)i * D + lane * 8 + 4) = oB;
}

// ---------------------------------------------------------------------------
extern "C" void kernel_launch(void* const* d_in, const int* in_sizes, int n_in,
                              void* d_out, int out_size, void* d_ws, size_t ws_size,
                              hipStream_t stream) {
  const float* x = (const float*)d_in[0];
  float* out = (float*)d_out;

  char* ws = (char*)d_ws;
  float* sq = (float*)ws;                              // 32 KB
  unsigned short* xb = (unsigned short*)(ws + 32768);  // 8 MB
  uint32* ck = (uint32*)(ws + 32768 + 8388608);        // 8 MB

  row_sq_np_kernel<<<N / 4, 256, 0, stream>>>(x, sq);
  cvt_bf16_kernel<<<(N * D) / (8 * 256), 256, 0, stream>>>(x, xb);
  knn_gemm_mfma<<<dim3(N / 128, GSPLIT), 256, 0, stream>>>(xb, sq, ck);
  merge_kernel<<<N / 4, 256, 0, stream>>>(x, sq, ck, out);
}

// Round 13
// 276.496 us; speedup vs baseline: 2.3922x; 2.3922x over previous
//
#include <hip/hip_runtime.h>

#define N 8192
#define D 512
#define KNEI 10
#define NC 8
#define GSPLIT 16
#define TRS 20
#define NTOT (GSPLIT * 2 * NC)  // 256 candidates per row

typedef __attribute__((ext_vector_type(8))) short bfv8;
typedef __attribute__((ext_vector_type(8))) unsigned short usv8;
typedef __attribute__((ext_vector_type(4))) float fv4;
typedef unsigned int uint32;

#define GLOAD_LDS16(gp, lp)                                                  \
  __builtin_amdgcn_global_load_lds(                                          \
      (const __attribute__((address_space(1))) void*)(gp),                   \
      (__attribute__((address_space(3))) void*)(lp), 16, 0, 0)

__device__ inline unsigned short f2bf(float f) {
  unsigned int u = __float_as_uint(f);
  return (unsigned short)((u + 0x7fffu + ((u >> 16) & 1u)) >> 16);
}

// ---------------------------------------------------------------------------
// Kernel 0: per-row fp32 sq (numpy-pairwise-style; validated rounds 3-12).
// ---------------------------------------------------------------------------
__global__ __launch_bounds__(256) void row_sq_np_kernel(const float* __restrict__ x,
                                                        float* __restrict__ sq) {
  const int wave = threadIdx.x >> 6;
  const int lane = threadIdx.x & 63;
  const int row = blockIdx.x * 4 + wave;
  const float* xr = x + (size_t)row * D;

  float s = 0.f;
  if (lane < 32) {
    const int leaf = lane >> 3;
    const int j = lane & 7;
    const float* a = xr + leaf * 128;
    float v = a[j];
    s = __fmul_rn(v, v);
#pragma unroll
    for (int i = 8; i < 128; i += 8) {
      v = a[i + j];
      s = __fadd_rn(s, __fmul_rn(v, v));
    }
  }
  float t1 = __shfl_xor(s, 1);
  s = __fadd_rn(s, t1);
  float t2 = __shfl_xor(s, 2);
  s = __fadd_rn(s, t2);
  float t4 = __shfl_xor(s, 4);
  s = __fadd_rn(s, t4);
  const float L0 = __shfl(s, 0);
  const float L1 = __shfl(s, 8);
  const float L2 = __shfl(s, 16);
  const float L3 = __shfl(s, 24);
  const float total = __fadd_rn(__fadd_rn(L0, L1), __fadd_rn(L2, L3));
  if (lane == 0) sq[row] = total;
}

// ---------------------------------------------------------------------------
// Kernel 0b: fp32 -> bf16 (RTNE).
// ---------------------------------------------------------------------------
__global__ __launch_bounds__(256) void cvt_bf16_kernel(const float* __restrict__ x,
                                                       unsigned short* __restrict__ xb) {
  const int base = (blockIdx.x * 256 + threadIdx.x) * 8;
  const float4 a = *(const float4*)(x + base);
  const float4 b = *(const float4*)(x + base + 4);
  usv8 o;
  o[0] = f2bf(a.x); o[1] = f2bf(a.y); o[2] = f2bf(a.z); o[3] = f2bf(a.w);
  o[4] = f2bf(b.x); o[5] = f2bf(b.y); o[6] = f2bf(b.z); o[7] = f2bf(b.w);
  *(usv8*)(xb + base) = o;
}

// ---------------------------------------------------------------------------
// Kernel 1: MFMA bf16 Gram + fused selection. Round-8 core (validated 142 µs)
// + phase-split score buffer Ct[32][136] (LDS 24.8 KB -> 6 blocks/CU) with
// FULLY STATIC acc indexing (r12's runtime acc[ph*2+f] caused a scratch
// spill: VGPR 40, WRITE_SIZE 2.3 GB). launch_bounds kept at (256,4) so the
// register budget is unchanged; occupancy gain comes from LDS only.
// ---------------------------------------------------------------------------
__global__ __launch_bounds__(256, 4) void knn_gemm_mfma(
    const unsigned short* __restrict__ xb, const float* __restrict__ sq,
    uint32* __restrict__ ck) {
  __shared__ __align__(16) char smem[24832];
  unsigned short* As = (unsigned short*)smem;            // 128x64 bf16 = 16384
  unsigned short* Bs = (unsigned short*)(smem + 16384);  // 64x64 bf16 =  8192
  float* Ct = (float*)smem;                              // [32][136] = 17408
  float* sqj_s = (float*)(smem + 24576);                 // 64 floats

  const int tid = threadIdx.x;
  const int lane = tid & 63;
  const int wave = tid >> 6;
  const int m = lane & 15;
  const int kg = lane >> 4;
  const int ibase = blockIdx.x * 128;
  const int jstart = blockIdx.y * (N / GSPLIT);

  const int srow = lane >> 3;
  const int schunk = lane & 7;
  const int sko = (schunk ^ srow) * 8;  // XOR-swizzled source k-offset

  uint32 bk[NC];
#pragma unroll
  for (int t = 0; t < NC; ++t) bk[t] = 0xffffffffu;

  const int selrow = tid & 127;
  const int selhalf = tid >> 7;
  const float sqi_own = sq[ibase + selrow];

  for (int jt = 0; jt < 8; ++jt) {
    const int jbase = jstart + jt * 64;

    fv4 acc[2][4];
#pragma unroll
    for (int fi = 0; fi < 2; ++fi)
#pragma unroll
      for (int fj = 0; fj < 4; ++fj) acc[fi][fj] = (fv4)(0.f);

    for (int kt = 0; kt < 8; ++kt) {
      const int k0 = kt * 64;
      __syncthreads();  // prior frag/Ct/sqj reads done; LDS reusable
      if (kt == 0 && tid < 64) sqj_s[tid] = sq[jbase + tid];
#pragma unroll
      for (int q = 0; q < 4; ++q) {
        const int rbase = wave * 8 + q * 32;
        GLOAD_LDS16(xb + (size_t)(ibase + rbase + srow) * D + k0 + sko,
                    As + rbase * 64);
      }
#pragma unroll
      for (int q = 0; q < 2; ++q) {
        const int rbase = wave * 8 + q * 32;
        GLOAD_LDS16(xb + (size_t)(jbase + rbase + srow) * D + k0 + sko,
                    Bs + rbase * 64);
      }
      __syncthreads();  // staging visible

      bfv8 af[2][2];
#pragma unroll
      for (int fi = 0; fi < 2; ++fi) {
        const int row = wave * 32 + fi * 16 + m;
#pragma unroll
        for (int kh = 0; kh < 2; ++kh) {
          const int ch = (kh * 4 + kg) ^ (row & 7);
          af[fi][kh] = *(const bfv8*)(As + row * 64 + ch * 8);
        }
      }
#pragma unroll
      for (int fj = 0; fj < 4; ++fj) {
        const int row = fj * 16 + m;
        const bfv8 b0 = *(const bfv8*)(Bs + row * 64 + ((kg ^ (row & 7)) * 8));
        const bfv8 b1 =
            *(const bfv8*)(Bs + row * 64 + (((4 + kg) ^ (row & 7)) * 8));
#pragma unroll
        for (int fi = 0; fi < 2; ++fi) {
          acc[fi][fj] = __builtin_amdgcn_mfma_f32_16x16x32_bf16(
              af[fi][0], b0, acc[fi][fj], 0, 0, 0);
          acc[fi][fj] = __builtin_amdgcn_mfma_f32_16x16x32_bf16(
              af[fi][1], b1, acc[fi][fj], 0, 0, 0);
        }
      }
    }

    // ---- Phase 0: cols 0..31 (acc[.][0], acc[.][1]) — static indices ----
    __syncthreads();  // frag reads done; Ct may overwrite staging
#pragma unroll
    for (int fi = 0; fi < 2; ++fi) {
      *(fv4*)(&Ct[(0 * 16 + m) * 136 + wave * 32 + fi * 16 + kg * 4]) =
          acc[fi][0];
      *(fv4*)(&Ct[(1 * 16 + m) * 136 + wave * 32 + fi * 16 + kg * 4]) =
          acc[fi][1];
    }
    __syncthreads();
    {
      const int cb = selhalf * 16;
#pragma unroll 1
      for (int cc = 0; cc < 16; ++cc) {
        const int cl = cb + cc;
        const float d = fmaxf(
            sqi_own - 2.f * Ct[cl * 136 + selrow] + sqj_s[cl], 0.f);
        const uint32 key =
            (__float_as_uint(d) & 0xffff0000u) | (uint32)(jbase + cl);
        if (key < bk[NC - 1]) {
          uint32 kv = key;
#pragma unroll
          for (int t = 0; t < NC; ++t) {
            if (kv < bk[t]) {
              const uint32 tmp = bk[t];
              bk[t] = kv;
              kv = tmp;
            }
          }
        }
      }
    }

    // ---- Phase 1: cols 32..63 (acc[.][2], acc[.][3]) — static indices ----
    __syncthreads();  // phase-0 scans done
#pragma unroll
    for (int fi = 0; fi < 2; ++fi) {
      *(fv4*)(&Ct[(0 * 16 + m) * 136 + wave * 32 + fi * 16 + kg * 4]) =
          acc[fi][2];
      *(fv4*)(&Ct[(1 * 16 + m) * 136 + wave * 32 + fi * 16 + kg * 4]) =
          acc[fi][3];
    }
    __syncthreads();
    {
      const int cb = selhalf * 16;
#pragma unroll 1
      for (int cc = 0; cc < 16; ++cc) {
        const int cl = cb + cc;
        const float d = fmaxf(
            sqi_own - 2.f * Ct[cl * 136 + selrow] + sqj_s[32 + cl], 0.f);
        const uint32 key =
            (__float_as_uint(d) & 0xffff0000u) | (uint32)(jbase + 32 + cl);
        if (key < bk[NC - 1]) {
          uint32 kv = key;
#pragma unroll
          for (int t = 0; t < NC; ++t) {
            if (kv < bk[t]) {
              const uint32 tmp = bk[t];
              bk[t] = kv;
              kv = tmp;
            }
          }
        }
      }
    }
  }

  const size_t obase =
      ((size_t)(ibase + selrow) * (GSPLIT * 2) + blockIdx.y * 2 + selhalf) * NC;
#pragma unroll
  for (int t = 0; t < NC; ++t) ck[obase + t] = bk[t];
}

// ---------------------------------------------------------------------------
// Kernel 2: wave-per-row merge (validated rounds 8/10/11/12; unchanged).
// ---------------------------------------------------------------------------
__global__ __launch_bounds__(256) void merge_kernel(const float* __restrict__ x,
                                                    const float* __restrict__ sq,
                                                    const uint32* __restrict__ ck,
                                                    float* __restrict__ out) {
  __shared__ double zsh[4][TRS];
  __shared__ int jsh[4][TRS];
  __shared__ int jout[4][KNEI];

  const int wave = threadIdx.x >> 6;
  const int lane = threadIdx.x & 63;
  const int i = blockIdx.x * 4 + wave;

  const float4 xiA = *(const float4*)(x + (size_t)i * D + lane * 8);
  const float4 xiB = *(const float4*)(x + (size_t)i * D + lane * 8 + 4);
  const float sqi = sq[i];

  const uint32* ckr = ck + (size_t)i * NTOT + lane * 4;
  uint32 l0 = ckr[0], l1 = ckr[1], l2 = ckr[2], l3 = ckr[3];

  // (1) top-20 by packed key (score bits, then lower index — keys unique).
  int myselj = 0;
#pragma unroll 1
  for (int slot = 0; slot < TRS; ++slot) {
    uint32 r = min(min(l0, l1), min(l2, l3));
#pragma unroll
    for (int off = 32; off; off >>= 1) r = min(r, __shfl_xor(r, off));
    if (lane == slot) myselj = (int)(r & 0xffffu);
    if (l0 == r) l0 = 0xffffffffu;
    if (l1 == r) l1 = 0xffffffffu;
    if (l2 == r) l2 = 0xffffffffu;
    if (l3 == r) l3 = 0xffffffffu;
  }

  // (2) fp64 rescore with the reference's fp32 rounding chain (validated).
  double myz = 0.0;
#pragma unroll 4
  for (int c = 0; c < TRS; ++c) {
    const int j = __shfl(myselj, c);
    const float4 a = *(const float4*)(x + (size_t)j * D + lane * 8);
    const float4 b = *(const float4*)(x + (size_t)j * D + lane * 8 + 4);
    double s = (double)xiA.x * a.x + (double)xiA.y * a.y +
               (double)xiA.z * a.z + (double)xiA.w * a.w +
               (double)xiB.x * b.x + (double)xiB.y * b.y +
               (double)xiB.z * b.z + (double)xiB.w * b.w;
#pragma unroll
    for (int off = 32; off; off >>= 1) s += __shfl_xor(s, off);
    if (lane == c) {
      const float G = (float)s;
      const float y = __fsub_rn(sqi, __fmul_rn(2.0f, G));
      myz = (double)y + (double)sq[j];
    }
  }
  if (lane < TRS) {
    zsh[wave][lane] = myz;
    jsh[wave][lane] = myselj;
  }
  __syncthreads();

  // (3) serial top-10, eps tie-break — comparator identical to rounds 3-12.
  if (lane == 0) {
    unsigned int used = 0u;
    for (int slot = 0; slot < KNEI; ++slot) {
      int b = -1;
      double zb = 0.0;
      for (int c = 0; c < TRS; ++c) {
        if ((used >> c) & 1u) continue;
        const double zc = zsh[wave][c];
        if (b < 0) {
          b = c;
          zb = zc;
          continue;
        }
        const double eps = 1.25e-7 * fabs(zb);
        bool better;
        if (zc < zb - eps) better = true;
        else if (zc > zb + eps) better = false;
        else better = (jsh[wave][c] < jsh[wave][b]);
        if (better) {
          b = c;
          zb = zc;
        }
      }
      used |= (1u << b);
      jout[wave][slot] = jsh[wave][b];
    }
  }
  __syncthreads();

  // (4) smoothed = 0.5*x + 0.05 * sum(neighbors); 8 dims per lane.
  float4 sA = {0.f, 0.f, 0.f, 0.f}, sB = {0.f, 0.f, 0.f, 0.f};
#pragma unroll
  for (int mth = 0; mth < KNEI; ++mth) {
    const int j = jout[wave][mth];
    const float4 a = *(const float4*)(x + (size_t)j * D + lane * 8);
    const float4 b = *(const float4*)(x + (size_t)j * D + lane * 8 + 4);
    sA.x += a.x; sA.y += a.y; sA.z += a.z; sA.w += a.w;
    sB.x += b.x; sB.y += b.y; sB.z += b.z; sB.w += b.w;
  }
  float4 oA, oB;
  oA.x = 0.5f * xiA.x + 0.05f * sA.x;
  oA.y = 0.5f * xiA.y + 0.05f * sA.y;
  oA.z = 0.5f * xiA.z + 0.05f * sA.z;
  oA.w = 0.5f * xiA.w + 0.05f * sA.w;
  oB.x = 0.5f * xiB.x + 0.05f * sB.x;
  oB.y = 0.5f * xiB.y + 0.05f * sB.y;
  oB.z = 0.5f * xiB.z + 0.05f * sB.z;
  oB.w = 0.5f * xiB.w + 0.05f * sB.w;
  *(float4*)(out + (size_t)i * D + lane * 8) = oA;
  *(float4*)(out + (size_t)i * D + lane * 8 + 4) = oB;
}

// ---------------------------------------------------------------------------
extern "C" void kernel_launch(void* const* d_in, const int* in_sizes, int n_in,
                              void* d_out, int out_size, void* d_ws, size_t ws_size,
                              hipStream_t stream) {
  const float* x = (const float*)d_in[0];
  float* out = (float*)d_out;

  char* ws = (char*)d_ws;
  float* sq = (float*)ws;                              // 32 KB
  unsigned short* xb = (unsigned short*)(ws + 32768);  // 8 MB
  uint32* ck = (uint32*)(ws + 32768 + 8388608);        // 8 MB

  row_sq_np_kernel<<<N / 4, 256, 0, stream>>>(x, sq);
  cvt_bf16_kernel<<<(N * D) / (8 * 256), 256, 0, stream>>>(x, xb);
  knn_gemm_mfma<<<dim3(N / 128, GSPLIT), 256, 0, stream>>>(xb, sq, ck);
  merge_kernel<<<N / 4, 256, 0, stream>>>(x, sq, ck, out);
}